// Round 10
// baseline (286.086 us; speedup 1.0000x reference)
//
#include <hip/hip_runtime.h>

#define B_  4
#define T_  2048
#define H_  16
#define DM_ 1024
#define DH_ 64
#define RK_ 32

using u16 = unsigned short;
using u32 = unsigned int;
typedef float  floatx4 __attribute__((ext_vector_type(4)));
typedef __bf16 bf16x8  __attribute__((ext_vector_type(8)));
typedef u16    u16x8   __attribute__((ext_vector_type(8)));
typedef u16    u16x4   __attribute__((ext_vector_type(4)));
typedef short  s16x4   __attribute__((ext_vector_type(4)));

#define MFMA16(a,b,c) __builtin_amdgcn_mfma_f32_16x16x32_bf16((a),(b),(c),0,0,0)
// K=16 bf16 MFMA: A/B frag = 4 bf16 (k = quad*4+j), C/D same 16x16 layout
#define MFMA1K(a,b,c) __builtin_amdgcn_mfma_f32_16x16x16bf16_1k((a),(b),(c),0,0,0)

__device__ __forceinline__ u16 f2bf(float f) {
  unsigned u = __float_as_uint(f);
  u += 0x7fffu + ((u >> 16) & 1u);   // RNE
  return (u16)(u >> 16);
}
// RNE pack: (bf16(b)<<16)|bf16(a)
__device__ __forceinline__ u32 pack_bf(float a, float b) {
  u32 ua = __float_as_uint(a); ua += 0x7fffu + ((ua >> 16) & 1u);
  u32 ub = __float_as_uint(b); ub += 0x7fffu + ((ub >> 16) & 1u);
  return __builtin_amdgcn_perm(ub, ua, 0x07060302u);
}
// truncation pack (1 instr) — for P in the hot loop (values > 0)
__device__ __forceinline__ u32 tpack(float a, float b) {
  return __builtin_amdgcn_perm(__float_as_uint(b), __float_as_uint(a), 0x07060302u);
}

// async global->LDS, 16B per lane. LDS dest is wave-uniform base; HW adds lane*16.
__device__ __forceinline__ void async_copy16(const u16* g, const u16* lds_uniform_base) {
  __builtin_amdgcn_global_load_lds(
      (const __attribute__((address_space(1))) unsigned int*)(unsigned long long)g,
      (__attribute__((address_space(3))) unsigned int*)(unsigned int)(unsigned long long)lds_uniform_base,
      16, 0, 0);
}

// ---------------- conversion ----------------
__global__ __launch_bounds__(256) void cvt_x(const float* __restrict__ s,
                                             u16* __restrict__ d, int n4) {
  int i = blockIdx.x * 256 + threadIdx.x;
  if (i >= n4) return;
  float4 v = reinterpret_cast<const float4*>(s)[i];
  u16x4 o = { f2bf(v.x), f2bf(v.y), f2bf(v.z), f2bf(v.w) };
  reinterpret_cast<u16x4*>(d)[i] = o;
}

// ---------------- fused weight prep: cvt Wv/Wo + LSR folds (one launch) ----------------
__global__ __launch_bounds__(256) void prep_w(const float* __restrict__ Wv,
                                              const float* __restrict__ Wo,
                                              const float* __restrict__ Wq,
                                              const float* __restrict__ bq,
                                              const float* __restrict__ Wql,
                                              const float* __restrict__ Wk,
                                              const float* __restrict__ bk,
                                              const float* __restrict__ Wkl,
                                              u16* __restrict__ Wcat,
                                              float* __restrict__ beffq,
                                              float* __restrict__ beffk) {
  const int tid = threadIdx.x;
  const int bid = blockIdx.x;
  __shared__ float lw[64];
  if (bid < 2048) {
    int i = bid * 256 + tid;
    int reg = i >> 18;
    const float* s = reg ? Wo : Wv;
    int j = i & 262143;
    float4 v = reinterpret_cast<const float4*>(s)[j];
    u16x4 o = { f2bf(v.x), f2bf(v.y), f2bf(v.z), f2bf(v.w) };
    reinterpret_cast<u16x4*>(Wcat)[(reg ? 524288 : 0) + j] = o;
    return;
  }
  const int sel = (bid >= 2560);
  const int hr = bid - (sel ? 2560 : 2048);       // 0..511
  const int h = hr >> 5, r = hr & 31;
  const float* W    = sel ? Wk : Wq;
  const float* bias = sel ? bk : bq;
  const float* lsr  = sel ? Wkl : Wql;
  const float fold  = sel ? 1.0f : 0.25506100790944405f;  // (1/sqrt(32))*log2(e)
  u16*   Weff = Wcat + (sel ? 1572864 : 1048576);
  float* beff = sel ? beffk : beffq;
  if (tid < 64) lw[tid] = lsr[(size_t)(h * 64 + tid) * 32 + r] * fold;
  __syncthreads();
  float a0 = 0.f, a1 = 0.f, a2 = 0.f, a3 = 0.f;
  for (int d = 0; d < 64; d++) {
    float l = lw[d];
    float4 wv = *reinterpret_cast<const float4*>(W + (size_t)(h * 64 + d) * 1024 + tid * 4);
    a0 += l * wv.x; a1 += l * wv.y; a2 += l * wv.z; a3 += l * wv.w;
  }
  u16x4 o = { f2bf(a0), f2bf(a1), f2bf(a2), f2bf(a3) };
  reinterpret_cast<u16x4*>(Weff)[(size_t)hr * 256 + tid] = o;
  if (tid == 0) {
    float s = 0.f;
    for (int d = 0; d < 64; d++) s += lw[d] * bias[h * 64 + d];
    beff[hr] = s;
  }
}

// ---------------- GEMM: C[M,N] = A[M,K] * W[N,K]^T + bias, K=1024 ----------------
// 128x128 tile, BK=64, double-buffered 64KB LDS with XOR-swizzle: conflict-free
// ds_read_b128 (verified 0 conflicts). global_load_lds with pre-swizzled source.
template <int MODE>
__global__ __launch_bounds__(256, 2) void gemm8(const u16* __restrict__ A,
                                                const u16* __restrict__ W,
                                                const float* __restrict__ b0,
                                                const float* __restrict__ b1,
                                                const float* __restrict__ b2,
                                                void* __restrict__ Cv,
                                                u16* __restrict__ qo,
                                                u16* __restrict__ ko,
                                                int ldc) {
  __shared__ __align__(16) u16 Al[2][8192];   // [buf][128 rows][64 k] swizzled
  __shared__ __align__(16) u16 Bl[2][8192];
  const int tid  = threadIdx.x;
  const int lane = tid & 63;
  const int w    = tid >> 6;
  const int quad = lane >> 4;
  const int l16  = lane & 15;
  const int wm   = (w >> 1) << 6;
  const int wn   = (w & 1) << 6;

  const int bm = blockIdx.x << 7;
  const int bn = blockIdx.y << 7;

  const int sr = tid >> 3;
  const int sc = ((tid & 7) ^ (sr & 7)) * 8;
  const u16* Ag = A + (size_t)(bm + sr) * 1024 + sc;
  const u16* Wg = W + (size_t)(bn + sr) * 1024 + sc;

  auto stage = [&](int k0, int bsel) {        // 8 vm ops / tile
#pragma unroll
    for (int j = 0; j < 4; j++)
      async_copy16(Ag + (size_t)j * 32768 + k0, &Al[bsel][j * 2048 + w * 512]);
#pragma unroll
    for (int j = 0; j < 4; j++)
      async_copy16(Wg + (size_t)j * 32768 + k0, &Bl[bsel][j * 2048 + w * 512]);
  };

  int aoff[4], boff[4], sl[2];
#pragma unroll
  for (int mi = 0; mi < 4; mi++) aoff[mi] = (wm + mi * 16 + l16) * 64;
#pragma unroll
  for (int ni = 0; ni < 4; ni++) boff[ni] = (wn + ni * 16 + l16) * 64;
  sl[0] = ((0 + quad) ^ (l16 & 7)) * 8;
  sl[1] = ((4 + quad) ^ (l16 & 7)) * 8;

  floatx4 acc[4][4];
#pragma unroll
  for (int i = 0; i < 4; i++)
#pragma unroll
    for (int j = 0; j < 4; j++) acc[i][j] = (floatx4){0.f, 0.f, 0.f, 0.f};

  stage(0, 0);
  asm volatile("s_waitcnt vmcnt(0)" ::: "memory");
  __builtin_amdgcn_s_barrier();
  asm volatile("" ::: "memory");

  for (int i = 0; i < 16; i++) {
    if (i < 15) stage((i + 1) * 64, (i + 1) & 1);
    const u16* Ab = Al[i & 1];
    const u16* Bb = Bl[i & 1];
#pragma unroll
    for (int ks = 0; ks < 2; ks++) {
      bf16x8 af[4], bfr[4];
#pragma unroll
      for (int mi = 0; mi < 4; mi++)
        af[mi] = *reinterpret_cast<const bf16x8*>(Ab + aoff[mi] + sl[ks]);
#pragma unroll
      for (int ni = 0; ni < 4; ni++)
        bfr[ni] = *reinterpret_cast<const bf16x8*>(Bb + boff[ni] + sl[ks]);
      __builtin_amdgcn_s_setprio(1);
#pragma unroll
      for (int mi = 0; mi < 4; mi++)
#pragma unroll
        for (int ni = 0; ni < 4; ni++)
          acc[mi][ni] = MFMA16(af[mi], bfr[ni], acc[mi][ni]);
      __builtin_amdgcn_s_setprio(0);
    }
    if (i < 15) {
      asm volatile("s_waitcnt vmcnt(0)" ::: "memory");   // tile i+1 landed
      __builtin_amdgcn_s_barrier();
      asm volatile("" ::: "memory");
    }
  }

  if (MODE == 1) {
#pragma unroll
    for (int ni = 0; ni < 4; ni++) {
      int col = bn + wn + ni * 16 + l16;
      float bias = b0[col & 1023];
#pragma unroll
      for (int mi = 0; mi < 4; mi++)
#pragma unroll
        for (int r = 0; r < 4; r++) {
          int row = bm + wm + mi * 16 + quad * 4 + r;
          reinterpret_cast<float*>(Cv)[(size_t)row * ldc + col] = acc[mi][ni][r] + bias;
        }
    }
  } else {
    if (bn < 1024) {
#pragma unroll
      for (int ni = 0; ni < 4; ni++) {
        int col = bn + wn + ni * 16 + l16;
        float bias = b0[col];
#pragma unroll
        for (int mi = 0; mi < 4; mi++)
#pragma unroll
          for (int r = 0; r < 4; r++) {
            int row = bm + wm + mi * 16 + quad * 4 + r;
            reinterpret_cast<u16*>(Cv)[(size_t)row * 1024 + col] =
                f2bf(acc[mi][ni][r] + bias);
          }
      }
    } else {
      u16* outp = (bn < 1536) ? qo : ko;
      const float* bp = (bn < 1536) ? b1 : b2;
#pragma unroll
      for (int ni = 0; ni < 4; ni++) {
        int cc = (bn + wn + ni * 16 + l16) & 511;
        float bias = bp[cc];
        int hh = cc >> 5, rk = cc & 31;
#pragma unroll
        for (int mi = 0; mi < 4; mi++)
#pragma unroll
          for (int r = 0; r < 4; r++) {
            int row = bm + wm + mi * 16 + quad * 4 + r;
            size_t addr =
                ((size_t)((row >> 11) * 16 + hh) * 2048 + (row & 2047)) * 32 + rk;
            outp[addr] = f2bf(acc[mi][ni][r] + bias);
          }
      }
    }
  }
}

// ---------------- V transpose: vt[bh][d][t] ----------------
__global__ __launch_bounds__(256) void vtrans(const u16* __restrict__ V,
                                              u16* __restrict__ vt) {
  const int tb = blockIdx.x;
  const int bh = blockIdx.y;
  const int b = bh >> 4, h = bh & 15;
  __shared__ u16 Vl[64][72];
  const int tid = threadIdx.x;
#pragma unroll
  for (int it = 0; it < 2; it++) {
    int c = it * 256 + tid;
    int t = c >> 3, dc = (c & 7) * 8;
    u16x8 v = *reinterpret_cast<const u16x8*>(
        V + (size_t)(b * T_ + tb * 64 + t) * 1024 + h * 64 + dc);
    *reinterpret_cast<u16x8*>(&Vl[t][dc]) = v;
  }
  __syncthreads();
#pragma unroll
  for (int it = 0; it < 2; it++) {
    int c = it * 256 + tid;
    int d = c >> 3, tt = (c & 7) * 8;
    u16x8 o;
#pragma unroll
    for (int j = 0; j < 8; j++) o[j] = Vl[tt + j][d];
    *reinterpret_cast<u16x8*>(vt + ((size_t)bh * 64 + d) * T_ + tb * 64 + tt) = o;
  }
}

// ---------------- flash attention v7: barrier-free, LDS-free, wave-autonomous ----------------
// R5-R9 invariant (6 variants, all 51-57us, MFMA-busy ~18us const, VALU-busy ~20us
// const, no pipe >40%): the cross-wave-sharing machinery (LDS tiles -> barrier/step
// -> vmcnt drains) IS the cost, not any one pipe. v7 deletes it: each WAVE owns 64
// q-rows and loads its own K/V fragments straight from L2 (K: 2 coalesced dwordx4
// per 32-key chunk; V: 8 dwordx2, 64B-aligned per V^T row -> full sector efficiency;
// ~2 TB/s per XCD, under the 4.3 ceiling). No __shared__, no s_barrier. In-wave
// even/odd register ping-pong issues chunk c+1's loads under chunk c's ~650cyc
// compute -> counted vmcnt waits emerge naturally. Triangular units dispatched
// heavy-first (LPT backfill, 512 blocks = 2/CU, 8 waves/CU).
__global__ __launch_bounds__(256, 2) void attn(const u16* __restrict__ qlr,
                                               const u16* __restrict__ klr,
                                               const u16* __restrict__ vt,
                                               u16* __restrict__ yatt) {
  const int bh = blockIdx.x;                      // XCD = bh%8 under round-robin
  const int b = bh >> 4, h = bh & 15;
  const int tid = threadIdx.x, lane = tid & 63, w = tid >> 6;
  const int quad = lane >> 4, l16 = lane & 15;
  const int u = 31 - (blockIdx.y * 4 + w);        // q-unit, heavy (u=31) first
  const int q0 = u * 64;

  const u16* qlr_bh = qlr + (size_t)bh * T_ * RK_;
  const u16* klr_bh = klr + (size_t)bh * T_ * RK_;
  const u16* vt_bh  = vt + (size_t)bh * 64 * T_;

  // Q fragments: q = q0 + qg*16 + l16, rk = quad*8..+7
  bf16x8 qf[4];
#pragma unroll
  for (int qg = 0; qg < 4; qg++)
    qf[qg] = *reinterpret_cast<const bf16x8*>(
        qlr_bh + (size_t)(q0 + qg * 16 + l16) * 32 + quad * 8);

  // K frag base: key = ck*32 + sub*16 + l16, rk = quad*8  (1KB coalesced per sub)
  const u16* kbase = klr_bh + (size_t)l16 * 32 + quad * 8;
  // V frag base: d = dt*16 + l16, keys ck*32 + sub*16 + quad*4..+3 (8B per lane)
  const u16* vbase = vt_bh + (size_t)l16 * 2048 + quad * 4;

  const floatx4 fzero = {0.f, 0.f, 0.f, 0.f};
  floatx4 oacc[4][4];                             // [dt][qg]
#pragma unroll
  for (int i = 0; i < 4; i++)
#pragma unroll
    for (int j = 0; j < 4; j++) oacc[i][j] = fzero;
  float rs[4] = {0.f, 0.f, 0.f, 0.f};

  bf16x8 kfA[2], kfB[2];                          // [sub]
  s16x4  vfA[4][2], vfB[4][2];                    // [dt][sub]

#define LOADK(dst, ck)                                                          \
  {                                                                             \
    _Pragma("unroll") for (int sub = 0; sub < 2; sub++)                         \
      dst[sub] = *reinterpret_cast<const bf16x8*>(                              \
          kbase + (size_t)((ck) * 32 + sub * 16) * 32);                         \
  }
#define LOADV(dst, ck)                                                          \
  {                                                                             \
    _Pragma("unroll") for (int dt = 0; dt < 4; dt++)                            \
      _Pragma("unroll") for (int sub = 0; sub < 2; sub++)                       \
        dst[dt][sub] = *reinterpret_cast<const s16x4*>(                         \
            vbase + (size_t)dt * 32768 + (ck) * 32 + sub * 16);                 \
  }
  // full (unmasked) chunk compute
#define COMPUTE_FULL(kf, vf)                                                    \
  {                                                                             \
    uint2 pk[2][4];                                                             \
    __builtin_amdgcn_s_setprio(1);                                              \
    _Pragma("unroll") for (int sub = 0; sub < 2; sub++)                         \
      _Pragma("unroll") for (int qg = 0; qg < 4; qg++) {                        \
        floatx4 sv = MFMA16(kf[sub], qf[qg], fzero);                            \
        float p0 = __builtin_amdgcn_exp2f(sv[0]);                               \
        float p1 = __builtin_amdgcn_exp2f(sv[1]);                               \
        float p2 = __builtin_amdgcn_exp2f(sv[2]);                               \
        float p3 = __builtin_amdgcn_exp2f(sv[3]);                               \
        rs[qg] += (p0 + p1) + (p2 + p3);                                        \
        pk[sub][qg].x = tpack(p0, p1);                                          \
        pk[sub][qg].y = tpack(p2, p3);                                          \
      }                                                                         \
    _Pragma("unroll") for (int dt = 0; dt < 4; dt++)                            \
      _Pragma("unroll") for (int sub = 0; sub < 2; sub++)                       \
        _Pragma("unroll") for (int qg = 0; qg < 4; qg++)                        \
          oacc[dt][qg] =                                                        \
              MFMA1K(vf[dt][sub], __builtin_bit_cast(s16x4, pk[sub][qg]),       \
                     oacc[dt][qg]);                                             \
    __builtin_amdgcn_s_setprio(0);                                              \
  }
  // masked chunk: qgd = qg with diagonal on sub0; qg<qgd full skipped here
  // (handled by caller ranges). For chunk with subs ks0,ks1 vs qs=4u+qg:
  //   qg: full if qs>ks, diag if qs==ks, zero if qs<ks.
#define SM_DIAG(kf_s, qg)                                                       \
  {                                                                             \
    floatx4 sv = MFMA16(kf_s, qf[qg], fzero);                                   \
    const int keyl = quad * 4;                                                  \
    float pr0 = (keyl + 0 <= l16) ? __builtin_amdgcn_exp2f(sv[0]) : 0.f;        \
    float pr1 = (keyl + 1 <= l16) ? __builtin_amdgcn_exp2f(sv[1]) : 0.f;        \
    float pr2 = (keyl + 2 <= l16) ? __builtin_amdgcn_exp2f(sv[2]) : 0.f;        \
    float pr3 = (keyl + 3 <= l16) ? __builtin_amdgcn_exp2f(sv[3]) : 0.f;        \
    rs[qg] += (pr0 + pr1) + (pr2 + pr3);                                        \
    pkm.x = tpack(pr0, pr1);                                                    \
    pkm.y = tpack(pr2, pr3);                                                    \
  }
#define SM_FULL(kf_s, qg)                                                       \
  {                                                                             \
    floatx4 sv = MFMA16(kf_s, qf[qg], fzero);                                   \
    float p0 = __builtin_amdgcn_exp2f(sv[0]);                                   \
    float p1 = __builtin_amdgcn_exp2f(sv[1]);                                   \
    float p2 = __builtin_amdgcn_exp2f(sv[2]);                                   \
    float p3 = __builtin_amdgcn_exp2f(sv[3]);                                   \
    rs[qg] += (p0 + p1) + (p2 + p3);                                            \
    pkm.x = tpack(p0, p1);                                                      \
    pkm.y = tpack(p2, p3);                                                      \
  }
#define PV_ONE(vf, sub, qg)                                                     \
  _Pragma("unroll") for (int dt = 0; dt < 4; dt++)                              \
    oacc[dt][qg] = MFMA1K(vf[dt][sub], __builtin_bit_cast(s16x4, pkm),          \
                          oacc[dt][qg]);

  // prologue: chunks 0 (A) and 1 (B) always exist (nck = 2u+2 >= 2)
  LOADK(kfA, 0); LOADV(vfA, 0);
  LOADK(kfB, 1); LOADV(vfB, 1);

  // main loop: full pairs {2t, 2t+1}, t = 0..u-1
  for (int t = 0; t < u; t++) {
    COMPUTE_FULL(kfA, vfA);
    LOADK(kfA, 2 * t + 2); LOADV(vfA, 2 * t + 2);   // covered by compute B
    COMPUTE_FULL(kfB, vfB);
    LOADK(kfB, 2 * t + 3); LOADV(vfB, 2 * t + 3);   // covered by next compute A
  }

  // epilogue: chunk 2u in A-regs (subs 4u, 4u+1), chunk 2u+1 in B-regs (4u+2, 4u+3)
  {
    uint2 pkm;
    // chunk 2u, sub0 (ks=4u): qg0 diag, qg1..3 full
    SM_DIAG(kfA[0], 0); PV_ONE(vfA, 0, 0);
    SM_FULL(kfA[0], 1); PV_ONE(vfA, 0, 1);
    SM_FULL(kfA[0], 2); PV_ONE(vfA, 0, 2);
    SM_FULL(kfA[0], 3); PV_ONE(vfA, 0, 3);
    // chunk 2u, sub1 (ks=4u+1): qg0 zero, qg1 diag, qg2..3 full
    SM_DIAG(kfA[1], 1); PV_ONE(vfA, 1, 1);
    SM_FULL(kfA[1], 2); PV_ONE(vfA, 1, 2);
    SM_FULL(kfA[1], 3); PV_ONE(vfA, 1, 3);
    // chunk 2u+1, sub0 (ks=4u+2): qg0,1 zero, qg2 diag, qg3 full
    SM_DIAG(kfB[0], 2); PV_ONE(vfB, 0, 2);
    SM_FULL(kfB[0], 3); PV_ONE(vfB, 0, 3);
    // chunk 2u+1, sub1 (ks=4u+3): qg0..2 zero, qg3 diag
    SM_DIAG(kfB[1], 3); PV_ONE(vfB, 1, 3);
  }

  // row-sum across quads; normalize; store O^T (d = dt*16 + quad*4 + r, q col l16)
#pragma unroll
  for (int qg = 0; qg < 4; qg++) {
    rs[qg] += __shfl_xor(rs[qg], 16);
    rs[qg] += __shfl_xor(rs[qg], 32);
  }
#pragma unroll
  for (int qg = 0; qg < 4; qg++) {
    float inv = 1.f / rs[qg];
    const int qrow = q0 + qg * 16 + l16;
#pragma unroll
    for (int dt = 0; dt < 4; dt++) {
      uint2 ov = { pack_bf(oacc[dt][qg][0] * inv, oacc[dt][qg][1] * inv),
                   pack_bf(oacc[dt][qg][2] * inv, oacc[dt][qg][3] * inv) };
      *reinterpret_cast<uint2*>(
          yatt + (size_t)(b * T_ + qrow) * 1024 + h * 64 + dt * 16 + quad * 4) = ov;
    }
  }
#undef LOADK
#undef LOADV
#undef COMPUTE_FULL
#undef SM_DIAG
#undef SM_FULL
#undef PV_ONE
}

// ---------------- launch ----------------
extern "C" void kernel_launch(void* const* d_in, const int* in_sizes, int n_in,
                              void* d_out, int out_size, void* d_ws, size_t ws_size,
                              hipStream_t stream) {
  const float* x   = (const float*)d_in[0];
  const float* Wq  = (const float*)d_in[1];
  const float* bq  = (const float*)d_in[2];
  const float* Wk  = (const float*)d_in[3];
  const float* bk  = (const float*)d_in[4];
  const float* Wv  = (const float*)d_in[5];
  const float* bv  = (const float*)d_in[6];
  const float* Wo  = (const float*)d_in[7];
  const float* bo  = (const float*)d_in[8];
  const float* Wql = (const float*)d_in[9];
  const float* Wkl = (const float*)d_in[10];
  float* out = (float*)d_out;

  char* ws = (char*)d_ws;
  u16*   xb    = (u16*)(ws);                  // 8192x1024 bf16 (16 MB) -- reused as vt
  u16*   Wcat  = (u16*)(ws + 16777216);       // 3072x1024 bf16 (6 MB): Wv | Weffq | Weffk | Wo
  float* beffq = (float*)(ws + 23068672);     // 512 f32
  float* beffk = (float*)(ws + 23072768);     // 512 f32
  u16*   Vbuf  = (u16*)(ws + 25165824);       // 8192x1024 bf16 (16 MB)
  u16*   qlr   = (u16*)(ws + 41943040);       // 64x2048x32 bf16 (8 MB)
  u16*   klr   = (u16*)(ws + 50331648);       // 64x2048x32 bf16 (8 MB)
  u16*   yatt  = (u16*)(ws + 58720256);       // 8192x1024 bf16 (16 MB)
  u16*   vt    = xb;                          // [bh][64][2048] bf16, after gemm0

  cvt_x<<<dim3(8192), 256, 0, stream>>>(x, xb, 2097152);
  prep_w<<<dim3(3072), 256, 0, stream>>>(Wv, Wo, Wq, bq, Wql, Wk, bk, Wkl,
                                         Wcat, beffq, beffk);
  gemm8<2><<<dim3(64, 16), 256, 0, stream>>>(xb, Wcat, bv, beffq, beffk,
                                             Vbuf, qlr, klr, 0);
  vtrans<<<dim3(32, 64), 256, 0, stream>>>(Vbuf, vt);
  attn<<<dim3(64, 8), 256, 0, stream>>>(qlr, klr, vt, yatt);
  gemm8<1><<<dim3(64, 8), 256, 0, stream>>>(yatt, Wcat + 2097152, bo, bo, bo,
                                            out, nullptr, nullptr, 1024);
}